// Round 9
// baseline (1037.230 us; speedup 1.0000x reference)
//
#include <hip/hip_runtime.h>
#include <math.h>

#define TWO_PI 6.28318530717958647692f
#define NXD 64
#define NYD 64
#define NZD 40
#define CID 32
#define NJZ 16   // kept z bins: kz = 0..7, 13..20
#define NJY 32   // kept y bins (xy branch): ky = 0..15, 17..32

// workspace slot strides (float2 elements per batch-slot)
#define R1SLOT 2621440ll   // max(T=2097152, S=2621440)
#define R2SLOT 655360ll    // max(V=524288, V2=655360)
#define R3SLOT 2621440ll   // max(P=2097152, P2=2621440, U=655360)

typedef __attribute__((ext_vector_type(8))) short short8;
typedef __attribute__((ext_vector_type(4))) float float4v;

__device__ inline unsigned short f2bf(float f) {
  unsigned u = __builtin_bit_cast(unsigned, f);
  unsigned r = (u + 0x7fffu + ((u >> 16) & 1u)) >> 16;
  return (unsigned short)r;
}
__device__ inline float bf2f(unsigned short h) {
  return __builtin_bit_cast(float, (unsigned)h << 16);
}

// ---------------- precomputed twiddle fragment tables (device globals)
__device__ __align__(16) unsigned short g_invyAH[2][4][64][8];  // [kt][yt][lane][j]
__device__ __align__(16) unsigned short g_invyAL[2][4][64][8];
__device__ __align__(16) unsigned short g_invzAH[3][64][8];     // [zt][lane][j]
__device__ __align__(16) unsigned short g_invzAL[3][64][8];
__device__ __align__(16) unsigned short g_fwdyB[2][4][64][8];   // [kt][nt][lane][j]
__device__ __align__(16) float2 g_ztw[NJZ][NZD];                // (cos, -sin) 2pi kz z/40

__global__ __launch_bounds__(256) void k_twprep() {
  int t = threadIdx.x;
  if (blockIdx.x == 0) {
    for (int idx = t; idx < 2 * 4 * 64 * 8; idx += 256) {
      int j = idx & 7, lane = (idx >> 3) & 63, yt = (idx >> 9) & 3, kt = idx >> 11;
      int l15 = lane & 15, quad = lane >> 4;
      int y = yt * 16 + l15;
      int k = kt * 32 + quad * 8 + j;
      int jy = k >> 1, part = k & 1;
      int ky = (jy < 16) ? jy : jy + 1;
      float s_, c_; sincosf(TWO_PI * ((ky * y) & 63) / 64.0f, &s_, &c_);
      float cj = (ky == 0 || ky == 32) ? 1.0f : 2.0f;
      cj *= (1.0f / 4096.0f);
      float val = part ? -cj * s_ : cj * c_;
      unsigned short h = f2bf(val);
      g_invyAH[kt][yt][lane][j] = h;
      g_invyAL[kt][yt][lane][j] = f2bf(val - bf2f(h));
    }
  } else if (blockIdx.x == 1) {
    for (int idx = t; idx < 2 * 4 * 64 * 8; idx += 256) {
      int j = idx & 7, lane = (idx >> 3) & 63, nt = (idx >> 9) & 3, kt = idx >> 11;
      int l15 = lane & 15, quad = lane >> 4;
      int n = nt * 16 + l15;
      int jy = n >> 1, part = n & 1;
      int ky = (jy < 16) ? jy : jy + 1;
      int y = kt * 32 + quad * 8 + j;
      float s_, c_; sincosf(TWO_PI * ((ky * y) & 63) / 64.0f, &s_, &c_);
      g_fwdyB[kt][nt][lane][j] = f2bf(part ? -s_ : c_);
    }
  } else if (blockIdx.x == 2) {
    for (int idx = t; idx < 3 * 64 * 8; idx += 256) {
      int j = idx & 7, lane = (idx >> 3) & 63, zt = idx >> 9;
      int l15 = lane & 15, quad = lane >> 4;
      int z = zt * 16 + l15;
      int k = quad * 8 + j;
      int jz = k >> 1, part = k & 1;
      int kz = (jz < 8) ? jz : jz + 5;
      float s_, c_; sincosf(TWO_PI * ((kz * z) % 40) / 40.0f, &s_, &c_);
      float cj = (kz == 0 || kz == 20) ? 1.0f : 2.0f;
      cj *= (1.0f / 2560.0f);
      float val = part ? -cj * s_ : cj * c_;
      unsigned short h = f2bf(val);
      g_invzAH[zt][lane][j] = h;
      g_invzAL[zt][lane][j] = f2bf(val - bf2f(h));
    }
  } else {
    for (int k = t; k < NJZ * NZD; k += 256) {
      int j = k / NZD, z = k % NZD;
      int kz = (j < 8) ? j : j + 5;
      int m = (kz * z) % NZD;
      float s_, c_; sincosf(TWO_PI * m / (float)NZD, &s_, &c_);
      g_ztw[j][z] = make_float2(c_, -s_);
    }
  }
}

// ---------------- z projection (shared by xz & yz branches), 4 xy per block
__global__ __launch_bounds__(512) void k_zproj(const float* __restrict__ X,
    float2* __restrict__ Tb, int b0) {
  __shared__ float xs[4][NZD][CID];
  __shared__ float2 tw[NJZ][NZD];
  int t = threadIdx.x;
  int xy0 = blockIdx.x * 4;
  int b = b0 + blockIdx.z;
  float2* T = Tb + (long)blockIdx.z * R1SLOT;
  const float4v* src = (const float4v*)(X + ((long)(b * 4096 + xy0)) * NZD * CID);
  float4v* xsf = (float4v*)&xs[0][0][0];
  for (int k = t; k < 1280; k += 512) xsf[k] = src[k];
  {
    const float2* gt = &g_ztw[0][0];
    for (int k = t; k < NJZ * NZD; k += 512) tw[k / NZD][k % NZD] = gt[k];
  }
  __syncthreads();
  int j = t >> 5, i = t & 31;
  float2 acc0 = make_float2(0.f, 0.f), acc1 = make_float2(0.f, 0.f);
  float2 acc2 = make_float2(0.f, 0.f), acc3 = make_float2(0.f, 0.f);
  for (int z = 0; z < NZD; ++z) {
    float2 w = tw[j][z];
    float v0 = xs[0][z][i], v1 = xs[1][z][i], v2 = xs[2][z][i], v3 = xs[3][z][i];
    acc0.x += v0 * w.x; acc0.y += v0 * w.y;
    acc1.x += v1 * w.x; acc1.y += v1 * w.y;
    acc2.x += v2 * w.x; acc2.y += v2 * w.y;
    acc3.x += v3 * w.x; acc3.y += v3 * w.y;
  }
  T[((long)(xy0 + 0) * NJZ + j) * CID + i] = acc0;
  T[((long)(xy0 + 1) * NJZ + j) * CID + i] = acc1;
  T[((long)(xy0 + 2) * NJZ + j) * CID + i] = acc2;
  T[((long)(xy0 + 3) * NJZ + j) * CID + i] = acc3;
}

// ---------------- streaming forward-axis DFT (64 -> 16 modes), amplification-free.
// mode-split: blockIdx.x = j*2 + mh; each block computes 8 modes (mh*8..mh*8+7).
__global__ __launch_bounds__(256) void k_fwddft(const float2* __restrict__ inb,
    float2* __restrict__ Ub, long CS, long SS, long JS) {
  __shared__ float2 tw[64];
  int t = threadIdx.x;
  if (t < 64) {
    float s_, c_; sincosf(TWO_PI * t / 64.0f, &s_, &c_);
    tw[t] = make_float2(c_, -s_);
  }
  int j = blockIdx.x >> 1, mh = blockIdx.x & 1, sc = blockIdx.y;
  int J = gridDim.x >> 1, SD = gridDim.y * 8;
  int m0 = mh * 8;
  int s = sc * 8 + (t >> 5), i = t & 31;
  const float2* in = inb + (long)blockIdx.z * R1SLOT + (long)j * JS + (long)s * SS + i;
  float2 acc[8];
#pragma unroll
  for (int m = 0; m < 8; ++m) acc[m] = make_float2(0.f, 0.f);
  __syncthreads();
#pragma unroll 4
  for (int c = 0; c < 64; ++c) {
    float2 v = in[(long)c * CS];
#pragma unroll
    for (int m = 0; m < 8; ++m) {
      float2 w = tw[((m0 + m) * c) & 63];
      acc[m].x += v.x * w.x - v.y * w.y;
      acc[m].y += v.x * w.y + v.y * w.x;
    }
  }
  float2* U = Ub + (long)blockIdx.z * R3SLOT;
#pragma unroll
  for (int m = 0; m < 8; ++m)
    U[((long)((m0 + m) * J + j) * SD + s) * 32 + i] = acc[m];
}

// ---------------- unified channel mode-mix: V[m,j,s,o] = sum_i U[m,j,s,i]*W[m,j][i][o]
__global__ __launch_bounds__(256) void k_mix(const float2* __restrict__ Ub,
    float2* __restrict__ Vb, const float* __restrict__ fw, const float* __restrict__ fw2,
    int jsplit, int JW, long OM, long OJ, long OS, int SD) {
  __shared__ float2 Us[64][32];
  __shared__ float2 Wm[32][32];
  int m = blockIdx.x, j = blockIdx.y, t = threadIdx.x;
  int J = gridDim.y;
  const float2* U = Ub + (long)blockIdx.z * R3SLOT + (long)(m * J + j) * SD * 32;
  for (int k = t; k < SD * 32; k += 256) Us[k >> 5][k & 31] = U[k];
  {
    const float* src = (j < jsplit) ? fw : fw2;
    int jl = (j < jsplit) ? j : j - jsplit;
    for (int k = t; k < 1024; k += 256) {
      int i = k >> 5, o = k & 31;
      const float* p = src + (((i * 32 + o) * 16 + m) * JW + jl) * 2;
      Wm[i][o] = make_float2(p[0], p[1]);
    }
  }
  __syncthreads();
  int o = t & 31, sg = t >> 5;
  float2* V = Vb + (long)blockIdx.z * R2SLOT;
  for (int s = sg; s < SD; s += 8) {
    float2 acc = make_float2(0.f, 0.f);
    for (int i2 = 0; i2 < 32; ++i2) {
      float2 u = Us[s][i2], w = Wm[i2][o];
      acc.x += u.x * w.x - u.y * w.y;
      acc.y += u.x * w.y + u.y * w.x;
    }
    V[(long)m * OM + (long)j * OJ + (long)s * OS + o] = acc;
  }
}

// ---------------- inverse axis DFT (16 modes -> 64), unnormalized
__global__ __launch_bounds__(256) void k_invaxis(const float2* __restrict__ Vb,
    float2* __restrict__ Pb) {
  __shared__ float2 Vs[16][CID];
  __shared__ float2 twp[64];
  int s = blockIdx.x, j = blockIdx.y, t = threadIdx.x;
  const float2* V = Vb + (long)blockIdx.z * R2SLOT;
  float2* P = Pb + (long)blockIdx.z * R3SLOT;
  if (t < 64) {
    float s_, c_; sincosf(TWO_PI * t / 64.0f, &s_, &c_);
    twp[t] = make_float2(c_, s_);
  }
  for (int k = t; k < 512; k += 256) {
    int mm = k >> 5, o = k & 31;
    Vs[mm][o] = V[((long)(mm * 64 + s) * NJZ + j) * CID + o];
  }
  __syncthreads();
  int o = t & 31, vg = t >> 5;
  for (int k = 0; k < 8; ++k) {
    int v = vg + 8 * k;
    float2 acc = make_float2(0.f, 0.f);
    for (int mm = 0; mm < 16; ++mm) {
      float2 w = twp[(mm * v) & 63];
      float2 vv = Vs[mm][o];
      acc.x += vv.x * w.x - vv.y * w.y;
      acc.y += vv.x * w.y + vv.y * w.x;
    }
    P[((long)(v * 64 + s) * NJZ + j) * CID + o] = acc;
  }
}

// ---------------- FUSED (lean): inverse real-z (xz branch) + 1x1 conv,
// WRITE-ONLY first writer of out. Same LDS/occupancy as plain invzadd;
// conv A-fragments loaded directly from global (coalesced), no extra staging.
__global__ __launch_bounds__(256) void k_invz_conv(const float2* __restrict__ Pb,
    const float* __restrict__ X, const float* __restrict__ Wc,
    const float* __restrict__ bias, float* __restrict__ out, int b0) {
  __shared__ __align__(16) char smem[21504]; // PsH+PsL=2*128*21*4=21504; Cs=40*132*4=21120
  unsigned (*PsH)[21] = (unsigned(*)[21])smem;
  unsigned (*PsL)[21] = (unsigned(*)[21])(smem + 10752);
  float (*Cs)[132] = (float(*)[132])smem;      // [z][m]
  int t = threadIdx.x;
  int wid = t >> 6, lane = t & 63;
  int l15 = lane & 15, quad = lane >> 4;
  int b = b0 + blockIdx.z;
  int vv = blockIdx.y;       // x
  int s0 = blockIdx.x * 4;   // y chunk
  // conv A fragments straight from global (rows of X this block owns)
  const float* xrow = X + ((long)(b * 4096 + vv * 64 + s0)) * (NZD * CID);
  short8 ca[3];
  int ntile = (wid < 2) ? 3 : 2;   // 10 tiles over 4 waves: wid, wid+4, wid+8(<10)
  for (int u = 0; u < ntile; ++u) {
    int rr = (wid + u * 4) * 16 + l15;
    const float4v* xp = (const float4v*)(xrow + rr * 32 + quad * 8);
    float4v x0 = xp[0], x1 = xp[1];
    for (int j = 0; j < 4; ++j) { ca[u][j] = (short)f2bf(x0[j]); ca[u][4 + j] = (short)f2bf(x1[j]); }
  }
  // invz A fragments + conv weights
  short8 AH[3], AL[3];
  for (int zt = 0; zt < 3; ++zt) {
    AH[zt] = *(const short8*)&g_invzAH[zt][lane][0];
    AL[zt] = *(const short8*)&g_invzAL[zt][lane][0];
  }
  short8 Bc[2]; float bb[2];
  for (int nt = 0; nt < 2; ++nt) {
    int o = nt * 16 + l15;
    for (int j = 0; j < 8; ++j) Bc[nt][j] = (short)f2bf(Wc[o * 32 + quad * 8 + j]);
    bb[nt] = bias[o];
  }
  // stage P_xz[vv, s0..s0+3, j, o] -> Ps[m = sl*32+o][j]
  const float2* src = Pb + (long)blockIdx.z * R3SLOT + ((long)(vv * 64 + s0) * NJZ) * CID;
  for (int kk = t; kk < 16 * 128; kk += 256) {
    int j = kk >> 7, m = kk & 127;
    int sl = m >> 5, o = m & 31;
    float2 v = src[((long)sl * NJZ + j) * CID + o];
    unsigned short hx = f2bf(v.x), hy = f2bf(v.y);
    unsigned short lx = f2bf(v.x - bf2f(hx)), ly = f2bf(v.y - bf2f(hy));
    PsH[m][j] = (unsigned)hx | ((unsigned)hy << 16);
    PsL[m][j] = (unsigned)lx | ((unsigned)ly << 16);
  }
  __syncthreads();
  // read B fragments to registers before overwriting the union with C
  short8 bh[2], bl[2];
  for (int mt = 0; mt < 2; ++mt) {
    int mc = wid * 32 + mt * 16 + l15;
    union { unsigned u[4]; short8 s; } th, tl;
    for (int c = 0; c < 4; ++c) {
      th.u[c] = PsH[mc][quad * 4 + c];
      tl.u[c] = PsL[mc][quad * 4 + c];
    }
    bh[mt] = th.s; bl[mt] = tl.s;
  }
  __syncthreads();
  // xz inverse-z GEMM -> Cs
  for (int mt = 0; mt < 2; ++mt) {
    int mc = wid * 32 + mt * 16;
    for (int zt = 0; zt < 3; ++zt) {
      float4v acc = {0.f, 0.f, 0.f, 0.f};
      acc = __builtin_amdgcn_mfma_f32_16x16x32_bf16(AL[zt], bh[mt], acc, 0, 0, 0);
      acc = __builtin_amdgcn_mfma_f32_16x16x32_bf16(AH[zt], bl[mt], acc, 0, 0, 0);
      acc = __builtin_amdgcn_mfma_f32_16x16x32_bf16(AH[zt], bh[mt], acc, 0, 0, 0);
      for (int r = 0; r < 4; ++r) {
        int z = zt * 16 + quad * 4 + r;
        if (z < 40) Cs[z][mc + l15] = acc[r];
      }
    }
  }
  __syncthreads();
  // conv MFMA adds (+bias) into Cs
  for (int u = 0; u < ntile; ++u) {
    int tile = wid + u * 4;
    for (int nt = 0; nt < 2; ++nt) {
      float4v acc = {0.f, 0.f, 0.f, 0.f};
      acc = __builtin_amdgcn_mfma_f32_16x16x32_bf16(ca[u], Bc[nt], acc, 0, 0, 0);
      for (int r = 0; r < 4; ++r) {
        int rg = tile * 16 + quad * 4 + r;
        int sl = rg / NZD, z = rg % NZD;
        Cs[z][sl * 32 + nt * 16 + l15] += acc[r] + bb[nt];
      }
    }
  }
  __syncthreads();
  // coalesced WRITE-ONLY epilogue: out[b][vv][s0+sl][z][o] = Cs[z][sl*32+o]
  float* obb = out + (long)b * (NXD * NYD * NZD * CID)
             + (long)vv * (NYD * NZD * CID) + (long)s0 * (NZD * CID);
  for (int idx = t; idx < 4 * 40 * 8; idx += 256) {
    int sl = idx / 320, rem = idx - sl * 320;
    int z = rem >> 3, o4 = rem & 7;
    *(float4v*)(obb + (long)sl * (NZD * CID) + z * 32 + o4 * 4) =
        *(const float4v*)&Cs[z][sl * 32 + o4 * 4];
  }
}

// ---------------- inverse real-z (yz branch) + accumulate (RMW), via MFMA GEMM.
__global__ __launch_bounds__(256) void k_invzadd_mfma(const float2* __restrict__ Pb,
    float* __restrict__ out, long strideV, long strideS, int b0) {
  __shared__ __align__(16) char smem[21504]; // PsH+PsL=2*128*21*4=21504; Cs=40*132*4=21120
  unsigned (*PsH)[21] = (unsigned(*)[21])smem;
  unsigned (*PsL)[21] = (unsigned(*)[21])(smem + 10752);
  float (*Cs)[132] = (float(*)[132])smem;      // [z][m]
  int t = threadIdx.x;
  int wid = t >> 6, lane = t & 63;
  int l15 = lane & 15, quad = lane >> 4;
  int b = b0 + blockIdx.z;
  int vv = blockIdx.y;
  int s0 = blockIdx.x * 4;
  short8 AH[3], AL[3];
  for (int zt = 0; zt < 3; ++zt) {
    AH[zt] = *(const short8*)&g_invzAH[zt][lane][0];
    AL[zt] = *(const short8*)&g_invzAL[zt][lane][0];
  }
  const float2* src = Pb + (long)blockIdx.z * R3SLOT + ((long)(vv * 64 + s0) * NJZ) * CID;
  for (int kk = t; kk < 16 * 128; kk += 256) {
    int j = kk >> 7, m = kk & 127;
    int sl = m >> 5, o = m & 31;
    float2 v = src[((long)sl * NJZ + j) * CID + o];
    unsigned short hx = f2bf(v.x), hy = f2bf(v.y);
    unsigned short lx = f2bf(v.x - bf2f(hx)), ly = f2bf(v.y - bf2f(hy));
    PsH[m][j] = (unsigned)hx | ((unsigned)hy << 16);
    PsL[m][j] = (unsigned)lx | ((unsigned)ly << 16);
  }
  __syncthreads();
  short8 bh[2], bl[2];
  for (int mt = 0; mt < 2; ++mt) {
    int mc = wid * 32 + mt * 16 + l15;
    union { unsigned u[4]; short8 s; } th, tl;
    for (int c = 0; c < 4; ++c) {
      th.u[c] = PsH[mc][quad * 4 + c];
      tl.u[c] = PsL[mc][quad * 4 + c];
    }
    bh[mt] = th.s; bl[mt] = tl.s;
  }
  __syncthreads();
  for (int mt = 0; mt < 2; ++mt) {
    int mc = wid * 32 + mt * 16;
    for (int zt = 0; zt < 3; ++zt) {
      float4v acc = {0.f, 0.f, 0.f, 0.f};
      acc = __builtin_amdgcn_mfma_f32_16x16x32_bf16(AL[zt], bh[mt], acc, 0, 0, 0);
      acc = __builtin_amdgcn_mfma_f32_16x16x32_bf16(AH[zt], bl[mt], acc, 0, 0, 0);
      acc = __builtin_amdgcn_mfma_f32_16x16x32_bf16(AH[zt], bh[mt], acc, 0, 0, 0);
      for (int r = 0; r < 4; ++r) {
        int z = zt * 16 + quad * 4 + r;
        if (z < 40) Cs[z][mc + l15] = acc[r];
      }
    }
  }
  __syncthreads();
  float* obb = out + (long)b * (NXD * NYD * NZD * CID) + (long)vv * strideV
             + (long)s0 * strideS;
  for (int idx = t; idx < 4 * 40 * 8; idx += 256) {
    int sl = idx / 320, rem = idx - sl * 320;
    int z = rem >> 3, o4 = rem & 7;
    float4v* gp = (float4v*)(obb + (long)sl * strideS + z * 32 + o4 * 4);
    float4v g = *gp;
    float4v c = *(const float4v*)&Cs[z][sl * 32 + o4 * 4];
    g.x += c.x; g.y += c.y; g.z += c.z; g.w += c.w;
    *gp = g;
  }
}

// ---------------- xy branch: forward real-y DFT via MFMA (64 -> 32 bins)
__global__ __launch_bounds__(256) void k_fwdy_mfma(const float* __restrict__ X,
    float2* __restrict__ Sb, int b0) {
  __shared__ __align__(16) char smem[35328]; // Xs=128*37*4=18944; Cs=128*69*4=35328
  unsigned (*Xs)[37] = (unsigned(*)[37])smem;   // [m][y2] packed bf16 pairs
  float (*Cs)[69] = (float(*)[69])smem;         // [m][n]
  int t = threadIdx.x;
  int wid = t >> 6, lane = t & 63;
  int l15 = lane & 15, quad = lane >> 4;
  int b = b0 + blockIdx.z;
  int x = blockIdx.y;
  int m0 = blockIdx.x * 128;
  short8 Bf[2][4];
  for (int kt = 0; kt < 2; ++kt)
    for (int nt = 0; nt < 4; ++nt)
      Bf[kt][nt] = *(const short8*)&g_fwdyB[kt][nt][lane][0];
  const float* src = X + (((long)b * 64 + x) * 64) * 1280 + m0;
  for (int k = t; k < 32 * 128; k += 256) {
    int y2 = k >> 7, m = k & 127;
    float v0 = src[(long)(2 * y2) * 1280 + m];
    float v1 = src[(long)(2 * y2 + 1) * 1280 + m];
    Xs[m][y2] = (unsigned)f2bf(v0) | ((unsigned)f2bf(v1) << 16);
  }
  __syncthreads();
  short8 a[2][2];
  for (int mt = 0; mt < 2; ++mt) {
    int mrow = wid * 32 + mt * 16 + l15;
    for (int kt = 0; kt < 2; ++kt) {
      union { unsigned u[4]; short8 s; } tmp;
      for (int c = 0; c < 4; ++c) tmp.u[c] = Xs[mrow][kt * 16 + quad * 4 + c];
      a[mt][kt] = tmp.s;
    }
  }
  __syncthreads();
  for (int mt = 0; mt < 2; ++mt) {
    for (int nt = 0; nt < 4; ++nt) {
      float4v acc = {0.f, 0.f, 0.f, 0.f};
      acc = __builtin_amdgcn_mfma_f32_16x16x32_bf16(a[mt][0], Bf[0][nt], acc, 0, 0, 0);
      acc = __builtin_amdgcn_mfma_f32_16x16x32_bf16(a[mt][1], Bf[1][nt], acc, 0, 0, 0);
      int n = nt * 16 + l15;
      for (int r = 0; r < 4; ++r)
        Cs[wid * 32 + mt * 16 + quad * 4 + r][n] = acc[r];
    }
  }
  __syncthreads();
  float2* S = Sb + (long)blockIdx.z * R1SLOT + (long)x * (NJY * NZD * CID) + m0;
  for (int idx = t; idx < 32 * 128; idx += 256) {
    int jy = idx >> 7, m = idx & 127;
    S[(long)jy * 1280 + m] = make_float2(Cs[m][2 * jy], Cs[m][2 * jy + 1]);
  }
}

// ---------------- xy branch: inverse x DFT (16 -> 64), unnormalized
__global__ __launch_bounds__(256) void k_invx_xy(const float2* __restrict__ V2b,
    float2* __restrict__ P2b) {
  __shared__ float2 Vs[16][CID];
  __shared__ float2 twp[64];
  int jy = blockIdx.x, z = blockIdx.y, t = threadIdx.x;
  const float2* V2 = V2b + (long)blockIdx.z * R2SLOT;
  float2* P2 = P2b + (long)blockIdx.z * R3SLOT;
  if (t < 64) {
    float s_, c_; sincosf(TWO_PI * t / 64.0f, &s_, &c_);
    twp[t] = make_float2(c_, s_);
  }
  for (int k = t; k < 512; k += 256) {
    int kx = k >> 5, o = k & 31;
    Vs[kx][o] = V2[(((long)kx * NJY + jy) * NZD + z) * CID + o];
  }
  __syncthreads();
  int o = t & 31, xg = t >> 5;
  for (int k = 0; k < 8; ++k) {
    int x = xg + 8 * k;
    float2 acc = make_float2(0.f, 0.f);
    for (int kx = 0; kx < 16; ++kx) {
      float2 w = twp[(kx * x) & 63];
      float2 v = Vs[kx][o];
      acc.x += v.x * w.x - v.y * w.y;
      acc.y += v.x * w.y + v.y * w.x;
    }
    P2[(((long)x * NJY + jy) * NZD + z) * CID + o] = acc;
  }
}

// ---------------- xy branch: inverse real-y (32 bins -> 64) + accumulate, via MFMA.
__global__ __launch_bounds__(256) void k_invyadd_mfma(const float2* __restrict__ P2b,
    float* __restrict__ out, int b0) {
  __shared__ __align__(16) char smem[18944]; // PsH+PsL=2*64*37*4=18944; Cs=64*68*4=17408
  unsigned (*PsH)[37] = (unsigned(*)[37])smem;      // [m][jy]
  unsigned (*PsL)[37] = (unsigned(*)[37])(smem + 9472);
  float (*Cs)[68] = (float(*)[68])smem;             // [y][m]
  int t = threadIdx.x;
  int wid = t >> 6, lane = t & 63;
  int l15 = lane & 15, quad = lane >> 4;
  int b = b0 + blockIdx.z;
  int x = blockIdx.y;
  int m0 = blockIdx.x * 64;                    // 1280 m / 64 = 20 blocks
  const float2* src = P2b + (long)blockIdx.z * R3SLOT + (long)x * (NJY * NZD * CID) + m0;
  for (int kk = t; kk < 32 * 64; kk += 256) {
    int jy = kk >> 6, m = kk & 63;
    float2 v = src[(long)jy * (NZD * CID) + m];
    unsigned short hx = f2bf(v.x), hy = f2bf(v.y);
    unsigned short lx = f2bf(v.x - bf2f(hx)), ly = f2bf(v.y - bf2f(hy));
    PsH[m][jy] = (unsigned)hx | ((unsigned)hy << 16);
    PsL[m][jy] = (unsigned)lx | ((unsigned)ly << 16);
  }
  __syncthreads();
  int mc = wid * 16;
  short8 bh0, bh1, bl0, bl1;
  {
    union { unsigned u[4]; short8 s; } t0, t1, t2, t3;
    for (int c = 0; c < 4; ++c) {
      t0.u[c] = PsH[mc + l15][quad * 4 + c];
      t1.u[c] = PsH[mc + l15][16 + quad * 4 + c];
      t2.u[c] = PsL[mc + l15][quad * 4 + c];
      t3.u[c] = PsL[mc + l15][16 + quad * 4 + c];
    }
    bh0 = t0.s; bh1 = t1.s; bl0 = t2.s; bl1 = t3.s;
  }
  __syncthreads();
#pragma unroll 1
  for (int yt = 0; yt < 4; ++yt) {
    short8 AH0 = *(const short8*)&g_invyAH[0][yt][lane][0];
    short8 AH1 = *(const short8*)&g_invyAH[1][yt][lane][0];
    short8 AL0 = *(const short8*)&g_invyAL[0][yt][lane][0];
    short8 AL1 = *(const short8*)&g_invyAL[1][yt][lane][0];
    float4v acc = {0.f, 0.f, 0.f, 0.f};
    acc = __builtin_amdgcn_mfma_f32_16x16x32_bf16(AL0, bh0, acc, 0, 0, 0);
    acc = __builtin_amdgcn_mfma_f32_16x16x32_bf16(AL1, bh1, acc, 0, 0, 0);
    acc = __builtin_amdgcn_mfma_f32_16x16x32_bf16(AH0, bl0, acc, 0, 0, 0);
    acc = __builtin_amdgcn_mfma_f32_16x16x32_bf16(AH1, bl1, acc, 0, 0, 0);
    acc = __builtin_amdgcn_mfma_f32_16x16x32_bf16(AH0, bh0, acc, 0, 0, 0);
    acc = __builtin_amdgcn_mfma_f32_16x16x32_bf16(AH1, bh1, acc, 0, 0, 0);
    for (int r = 0; r < 4; ++r) {
      int y = yt * 16 + quad * 4 + r;
      Cs[y][mc + l15] = acc[r];
    }
  }
  __syncthreads();
  float* ob = out + ((long)(b * 64 + x)) * (NYD * NZD * CID) + m0;
  for (int idx = t; idx < 64 * 16; idx += 256) {
    int y = idx >> 4, f = idx & 15;
    float4v* gp = (float4v*)(ob + (long)y * (NZD * CID) + f * 4);
    float4v g = *gp;
    float4v c = *(const float4v*)&Cs[y][f * 4];
    g.x += c.x; g.y += c.y; g.z += c.z; g.w += c.w;
    *gp = g;
  }
}

// ---------------- FFN via MFMA, in-place on out.
__global__ __launch_bounds__(256) void k_ff_mfma(float* __restrict__ out,
    const float* __restrict__ W0, const float* __restrict__ b0,
    const float* __restrict__ W1, const float* __restrict__ b1) {
  __shared__ unsigned short h1s[4][16 * 64];
  int t = threadIdx.x;
  int wid = t >> 6, lane = t & 63;
  int l15 = lane & 15, quad = lane >> 4;
  short8 B1[4];
  float bb0[4];
  for (int nt = 0; nt < 4; ++nt) {
    int hh = nt * 16 + l15;
    for (int j = 0; j < 8; ++j) B1[nt][j] = (short)f2bf(W0[hh * 32 + quad * 8 + j]);
    bb0[nt] = b0[hh];
  }
  short8 B2[2][2];
  float bb1[2];
  for (int k0 = 0; k0 < 2; ++k0)
    for (int nt = 0; nt < 2; ++nt) {
      int o = nt * 16 + l15;
      for (int j = 0; j < 8; ++j)
        B2[k0][nt][j] = (short)f2bf(W1[o * 64 + k0 * 32 + quad * 8 + j]);
    }
  for (int nt = 0; nt < 2; ++nt) bb1[nt] = b1[nt * 16 + l15];

  const int TOT = 40960;
  int wg = blockIdx.x * 4 + wid;
  unsigned short* hs = h1s[wid];
  for (int tt = wg; tt < TOT; tt += gridDim.x * 4) {
    long r0 = (long)tt * 16;
    const float4v* p = (const float4v*)(out + (r0 + l15) * 32 + quad * 8);
    float4v x0 = p[0], x1 = p[1];
    short8 a1;
    for (int j = 0; j < 4; ++j) { a1[j] = (short)f2bf(x0[j]); a1[4 + j] = (short)f2bf(x1[j]); }
    for (int nt = 0; nt < 4; ++nt) {
      float4v acc = {0.f, 0.f, 0.f, 0.f};
      acc = __builtin_amdgcn_mfma_f32_16x16x32_bf16(a1, B1[nt], acc, 0, 0, 0);
      for (int r = 0; r < 4; ++r) {
        float v = acc[r] + bb0[nt];
        v = v > 0.f ? v : 0.f;
        hs[(quad * 4 + r) * 64 + nt * 16 + l15] = f2bf(v);
      }
    }
    short8 a2[2];
    for (int k0 = 0; k0 < 2; ++k0)
      a2[k0] = *(const short8*)&hs[l15 * 64 + k0 * 32 + quad * 8];
    for (int nt = 0; nt < 2; ++nt) {
      float4v acc = {0.f, 0.f, 0.f, 0.f};
      acc = __builtin_amdgcn_mfma_f32_16x16x32_bf16(a2[0], B2[0][nt], acc, 0, 0, 0);
      acc = __builtin_amdgcn_mfma_f32_16x16x32_bf16(a2[1], B2[1][nt], acc, 0, 0, 0);
      for (int r = 0; r < 4; ++r)
        out[(r0 + quad * 4 + r) * 32 + nt * 16 + l15] = acc[r] + bb1[nt];
    }
  }
}

extern "C" void kernel_launch(void* const* d_in, const int* in_sizes, int n_in,
                              void* d_out, int out_size, void* d_ws, size_t ws_size,
                              hipStream_t stream) {
  const float* X       = (const float*)d_in[0];
  const float* w_w     = (const float*)d_in[1];
  const float* w_b     = (const float*)d_in[2];
  const float* fw_xy   = (const float*)d_in[3];
  const float* fw_yz   = (const float*)d_in[4];
  const float* fw_xz   = (const float*)d_in[5];
  const float* fw2_xy  = (const float*)d_in[6];
  const float* fw2_yz  = (const float*)d_in[7];
  const float* fw2_xz  = (const float*)d_in[8];
  const float* ff_w0   = (const float*)d_in[9];
  const float* ff_b0   = (const float*)d_in[10];
  const float* ff_w1   = (const float*)d_in[11];
  const float* ff_b1   = (const float*)d_in[12];
  float* out = (float*)d_out;
  char* ws = (char*)d_ws;

  const size_t need_full = (size_t)(R1SLOT + R2SLOT + R3SLOT) * 4 * 8;
  bool full = ws_size >= need_full;

  float2 *r1, *r2, *r3;
  if (full) {
    r1 = (float2*)ws;
    r2 = (float2*)(ws + (size_t)R1SLOT * 4 * 8);
    r3 = (float2*)(ws + (size_t)(R1SLOT + R2SLOT) * 4 * 8);
  } else {
    r1 = (float2*)ws;
    r2 = (float2*)(ws + (size_t)R1SLOT * 8);
    r3 = (float2*)(ws + (size_t)(R1SLOT + R2SLOT) * 8);
  }

  k_twprep<<<dim3(4), dim3(256), 0, stream>>>();

  int nz = full ? 4 : 1;
  int nb = full ? 1 : 4;
  for (int b = 0; b < nb; ++b) {
    // shared z-projection for xz & yz (T in r1)
    k_zproj<<<dim3(1024, 1, nz), dim3(512), 0, stream>>>(X, r1, b);
    // ---- xz branch: contract x. T idx: x*32768 + y*512 + j*32 + i
    k_fwddft<<<dim3(32, 8, nz), dim3(256), 0, stream>>>(r1, r3, 32768, 512, 32);
    k_mix<<<dim3(16, 16, nz), dim3(256), 0, stream>>>(r3, r2, fw_xz, fw2_xz,
        8, 8, 32768, 32, 512, 64);
    k_invaxis<<<dim3(64, 16, nz), dim3(256), 0, stream>>>(r2, r3);
    // fused invz(xz) + conv: WRITE-ONLY first writer of out
    k_invz_conv<<<dim3(16, 64, nz), dim3(256), 0, stream>>>(r3, X, w_w, w_b, out, b);
    // ---- yz branch: contract y. T idx: y*512 + x*32768 + j*32 + i
    k_fwddft<<<dim3(32, 8, nz), dim3(256), 0, stream>>>(r1, r3, 512, 32768, 32);
    k_mix<<<dim3(16, 16, nz), dim3(256), 0, stream>>>(r3, r2, fw_yz, fw2_yz,
        8, 8, 32768, 32, 512, 64);
    k_invaxis<<<dim3(64, 16, nz), dim3(256), 0, stream>>>(r2, r3);
    k_invzadd_mfma<<<dim3(16, 64, nz), dim3(256), 0, stream>>>(r3, out, 40 * 32, 64 * 40 * 32, b);
    // ---- xy branch (S in r1): S idx: x*40960 + jy*1280 + z*32 + i
    k_fwdy_mfma<<<dim3(10, 64, nz), dim3(256), 0, stream>>>(X, r1, b);
    k_fwddft<<<dim3(64, 5, nz), dim3(256), 0, stream>>>(r1, r3, 40960, 32, 1280);
    k_mix<<<dim3(16, 32, nz), dim3(256), 0, stream>>>(r3, r2, fw_xy, fw2_xy,
        16, 16, 40960, 1280, 32, 40);
    k_invx_xy<<<dim3(32, 40, nz), dim3(256), 0, stream>>>(r2, r3);
    k_invyadd_mfma<<<dim3(20, 64, nz), dim3(256), 0, stream>>>(r3, out, b);
  }

  k_ff_mfma<<<dim3(2560), dim3(256), 0, stream>>>(out, ff_w0, ff_b0, ff_w1, ff_b1);
}

// Round 10
// 726.927 us; speedup vs baseline: 1.4269x; 1.4269x over previous
//
#include <hip/hip_runtime.h>
#include <math.h>

#define TWO_PI 6.28318530717958647692f
#define NXD 64
#define NYD 64
#define NZD 40
#define CID 32
#define NJZ 16   // kept z bins: kz = 0..7, 13..20
#define NJY 32   // kept y bins (xy branch): ky = 0..15, 17..32

// workspace slot strides (float2 elements per batch-slot)
#define R1SLOT 2621440ll   // max(T=2097152, S=2621440)
#define R2SLOT 655360ll    // max(V=524288, V2=655360)
#define R3SLOT 2621440ll   // max(P=2097152, P2=2621440, U=655360)

typedef __attribute__((ext_vector_type(8))) short short8;
typedef __attribute__((ext_vector_type(4))) float float4v;

__device__ inline unsigned short f2bf(float f) {
  unsigned u = __builtin_bit_cast(unsigned, f);
  unsigned r = (u + 0x7fffu + ((u >> 16) & 1u)) >> 16;
  return (unsigned short)r;
}
__device__ inline float bf2f(unsigned short h) {
  return __builtin_bit_cast(float, (unsigned)h << 16);
}

// ---------------- precomputed twiddle fragment tables (device globals)
__device__ __align__(16) unsigned short g_invyAH[2][4][64][8];  // [kt][yt][lane][j]
__device__ __align__(16) unsigned short g_invyAL[2][4][64][8];
__device__ __align__(16) unsigned short g_invzAH[3][64][8];     // [zt][lane][j]
__device__ __align__(16) unsigned short g_invzAL[3][64][8];
__device__ __align__(16) unsigned short g_fwdyB[2][4][64][8];   // [kt][nt][lane][j]
__device__ __align__(16) float2 g_ztw[NJZ][NZD];                // (cos, -sin) 2pi kz z/40

__global__ __launch_bounds__(256) void k_twprep() {
  int t = threadIdx.x;
  if (blockIdx.x == 0) {
    // invy A: A[y][k] with y=yt*16+l15, k=kt*32+quad*8+j
    for (int idx = t; idx < 2 * 4 * 64 * 8; idx += 256) {
      int j = idx & 7, lane = (idx >> 3) & 63, yt = (idx >> 9) & 3, kt = idx >> 11;
      int l15 = lane & 15, quad = lane >> 4;
      int y = yt * 16 + l15;
      int k = kt * 32 + quad * 8 + j;
      int jy = k >> 1, part = k & 1;
      int ky = (jy < 16) ? jy : jy + 1;
      float s_, c_; sincosf(TWO_PI * ((ky * y) & 63) / 64.0f, &s_, &c_);
      float cj = (ky == 0 || ky == 32) ? 1.0f : 2.0f;
      cj *= (1.0f / 4096.0f);
      float val = part ? -cj * s_ : cj * c_;
      unsigned short h = f2bf(val);
      g_invyAH[kt][yt][lane][j] = h;
      g_invyAL[kt][yt][lane][j] = f2bf(val - bf2f(h));
    }
  } else if (blockIdx.x == 1) {
    // fwdy B: B[y][n] with n=nt*16+l15, y=kt*32+quad*8+j
    for (int idx = t; idx < 2 * 4 * 64 * 8; idx += 256) {
      int j = idx & 7, lane = (idx >> 3) & 63, nt = (idx >> 9) & 3, kt = idx >> 11;
      int l15 = lane & 15, quad = lane >> 4;
      int n = nt * 16 + l15;
      int jy = n >> 1, part = n & 1;
      int ky = (jy < 16) ? jy : jy + 1;
      int y = kt * 32 + quad * 8 + j;
      float s_, c_; sincosf(TWO_PI * ((ky * y) & 63) / 64.0f, &s_, &c_);
      g_fwdyB[kt][nt][lane][j] = f2bf(part ? -s_ : c_);
    }
  } else if (blockIdx.x == 2) {
    // invz A: A[z][k] with z=zt*16+l15, k=quad*8+j
    for (int idx = t; idx < 3 * 64 * 8; idx += 256) {
      int j = idx & 7, lane = (idx >> 3) & 63, zt = idx >> 9;
      int l15 = lane & 15, quad = lane >> 4;
      int z = zt * 16 + l15;
      int k = quad * 8 + j;
      int jz = k >> 1, part = k & 1;
      int kz = (jz < 8) ? jz : jz + 5;
      float s_, c_; sincosf(TWO_PI * ((kz * z) % 40) / 40.0f, &s_, &c_);
      float cj = (kz == 0 || kz == 20) ? 1.0f : 2.0f;
      cj *= (1.0f / 2560.0f);
      float val = part ? -cj * s_ : cj * c_;
      unsigned short h = f2bf(val);
      g_invzAH[zt][lane][j] = h;
      g_invzAL[zt][lane][j] = f2bf(val - bf2f(h));
    }
  } else {
    // zproj twiddles: (cos, -sin) of 2pi (kz*z mod 40)/40
    for (int k = t; k < NJZ * NZD; k += 256) {
      int j = k / NZD, z = k % NZD;
      int kz = (j < 8) ? j : j + 5;
      int m = (kz * z) % NZD;
      float s_, c_; sincosf(TWO_PI * m / (float)NZD, &s_, &c_);
      g_ztw[j][z] = make_float2(c_, -s_);
    }
  }
}

// ---------------- 1x1 conv via MFMA
__global__ __launch_bounds__(256) void k_conv_mfma(const float* __restrict__ X,
    const float* __restrict__ Wc, const float* __restrict__ bias,
    float* __restrict__ out) {
  int t = threadIdx.x;
  int wid = t >> 6, lane = t & 63;
  int l15 = lane & 15, quad = lane >> 4;
  short8 B[2];
  float bb[2];
  for (int nt = 0; nt < 2; ++nt) {
    int o = nt * 16 + l15;
    for (int j = 0; j < 8; ++j) B[nt][j] = (short)f2bf(Wc[o * 32 + quad * 8 + j]);
    bb[nt] = bias[o];
  }
  const int TOT = 40960;
  int wg = blockIdx.x * 4 + wid;
  for (int tt = wg; tt < TOT; tt += gridDim.x * 4) {
    long r0 = (long)tt * 16;
    const float4v* p = (const float4v*)(X + (r0 + l15) * 32 + quad * 8);
    float4v x0 = p[0], x1 = p[1];
    short8 a;
    for (int j = 0; j < 4; ++j) { a[j] = (short)f2bf(x0[j]); a[4 + j] = (short)f2bf(x1[j]); }
    for (int nt = 0; nt < 2; ++nt) {
      float4v acc = {0.f, 0.f, 0.f, 0.f};
      acc = __builtin_amdgcn_mfma_f32_16x16x32_bf16(a, B[nt], acc, 0, 0, 0);
      for (int r = 0; r < 4; ++r)
        out[(r0 + quad * 4 + r) * 32 + nt * 16 + l15] = acc[r] + bb[nt];
    }
  }
}

// ---------------- z projection (shared by xz & yz branches), 4 xy per block
__global__ __launch_bounds__(512) void k_zproj(const float* __restrict__ X,
    float2* __restrict__ Tb, int b0) {
  __shared__ float xs[4][NZD][CID];
  __shared__ float2 tw[NJZ][NZD];
  int t = threadIdx.x;
  int xy0 = blockIdx.x * 4;
  int b = b0 + blockIdx.z;
  float2* T = Tb + (long)blockIdx.z * R1SLOT;
  // vectorized staging: 4*40*32 floats contiguous = 1280 float4
  const float4v* src = (const float4v*)(X + ((long)(b * 4096 + xy0)) * NZD * CID);
  float4v* xsf = (float4v*)&xs[0][0][0];
  for (int k = t; k < 1280; k += 512) xsf[k] = src[k];
  {
    const float2* gt = &g_ztw[0][0];
    for (int k = t; k < NJZ * NZD; k += 512) tw[k / NZD][k % NZD] = gt[k];
  }
  __syncthreads();
  int j = t >> 5, i = t & 31;
  float2 acc0 = make_float2(0.f, 0.f), acc1 = make_float2(0.f, 0.f);
  float2 acc2 = make_float2(0.f, 0.f), acc3 = make_float2(0.f, 0.f);
  for (int z = 0; z < NZD; ++z) {
    float2 w = tw[j][z];
    float v0 = xs[0][z][i], v1 = xs[1][z][i], v2 = xs[2][z][i], v3 = xs[3][z][i];
    acc0.x += v0 * w.x; acc0.y += v0 * w.y;
    acc1.x += v1 * w.x; acc1.y += v1 * w.y;
    acc2.x += v2 * w.x; acc2.y += v2 * w.y;
    acc3.x += v3 * w.x; acc3.y += v3 * w.y;
  }
  T[((long)(xy0 + 0) * NJZ + j) * CID + i] = acc0;
  T[((long)(xy0 + 1) * NJZ + j) * CID + i] = acc1;
  T[((long)(xy0 + 2) * NJZ + j) * CID + i] = acc2;
  T[((long)(xy0 + 3) * NJZ + j) * CID + i] = acc3;
}

// ---------------- streaming forward-axis DFT (64 -> 16 modes), amplification-free.
// mode-split: blockIdx.x = j*2 + mh; each block computes 8 modes (mh*8..mh*8+7).
__global__ __launch_bounds__(256) void k_fwddft(const float2* __restrict__ inb,
    float2* __restrict__ Ub, long CS, long SS, long JS) {
  __shared__ float2 tw[64];
  int t = threadIdx.x;
  if (t < 64) {
    float s_, c_; sincosf(TWO_PI * t / 64.0f, &s_, &c_);
    tw[t] = make_float2(c_, -s_);
  }
  int j = blockIdx.x >> 1, mh = blockIdx.x & 1, sc = blockIdx.y;
  int J = gridDim.x >> 1, SD = gridDim.y * 8;
  int m0 = mh * 8;
  int s = sc * 8 + (t >> 5), i = t & 31;
  const float2* in = inb + (long)blockIdx.z * R1SLOT + (long)j * JS + (long)s * SS + i;
  float2 acc[8];
#pragma unroll
  for (int m = 0; m < 8; ++m) acc[m] = make_float2(0.f, 0.f);
  __syncthreads();
#pragma unroll 4
  for (int c = 0; c < 64; ++c) {
    float2 v = in[(long)c * CS];
#pragma unroll
    for (int m = 0; m < 8; ++m) {
      float2 w = tw[((m0 + m) * c) & 63];
      acc[m].x += v.x * w.x - v.y * w.y;
      acc[m].y += v.x * w.y + v.y * w.x;
    }
  }
  float2* U = Ub + (long)blockIdx.z * R3SLOT;
#pragma unroll
  for (int m = 0; m < 8; ++m)
    U[((long)((m0 + m) * J + j) * SD + s) * 32 + i] = acc[m];
}

// ---------------- unified channel mode-mix: V[m,j,s,o] = sum_i U[m,j,s,i]*W[m,j][i][o]
__global__ __launch_bounds__(256) void k_mix(const float2* __restrict__ Ub,
    float2* __restrict__ Vb, const float* __restrict__ fw, const float* __restrict__ fw2,
    int jsplit, int JW, long OM, long OJ, long OS, int SD) {
  __shared__ float2 Us[64][32];
  __shared__ float2 Wm[32][32];
  int m = blockIdx.x, j = blockIdx.y, t = threadIdx.x;
  int J = gridDim.y;
  const float2* U = Ub + (long)blockIdx.z * R3SLOT + (long)(m * J + j) * SD * 32;
  for (int k = t; k < SD * 32; k += 256) Us[k >> 5][k & 31] = U[k];
  {
    const float* src = (j < jsplit) ? fw : fw2;
    int jl = (j < jsplit) ? j : j - jsplit;
    for (int k = t; k < 1024; k += 256) {
      int i = k >> 5, o = k & 31;
      const float* p = src + (((i * 32 + o) * 16 + m) * JW + jl) * 2;
      Wm[i][o] = make_float2(p[0], p[1]);
    }
  }
  __syncthreads();
  int o = t & 31, sg = t >> 5;
  float2* V = Vb + (long)blockIdx.z * R2SLOT;
  for (int s = sg; s < SD; s += 8) {
    float2 acc = make_float2(0.f, 0.f);
    for (int i2 = 0; i2 < 32; ++i2) {
      float2 u = Us[s][i2], w = Wm[i2][o];
      acc.x += u.x * w.x - u.y * w.y;
      acc.y += u.x * w.y + u.y * w.x;
    }
    V[(long)m * OM + (long)j * OJ + (long)s * OS + o] = acc;
  }
}

// ---------------- inverse axis DFT (16 modes -> 64), unnormalized
__global__ __launch_bounds__(256) void k_invaxis(const float2* __restrict__ Vb,
    float2* __restrict__ Pb) {
  __shared__ float2 Vs[16][CID];
  __shared__ float2 twp[64];
  int s = blockIdx.x, j = blockIdx.y, t = threadIdx.x;
  const float2* V = Vb + (long)blockIdx.z * R2SLOT;
  float2* P = Pb + (long)blockIdx.z * R3SLOT;
  if (t < 64) {
    float s_, c_; sincosf(TWO_PI * t / 64.0f, &s_, &c_);
    twp[t] = make_float2(c_, s_);
  }
  for (int k = t; k < 512; k += 256) {
    int mm = k >> 5, o = k & 31;
    Vs[mm][o] = V[((long)(mm * 64 + s) * NJZ + j) * CID + o];
  }
  __syncthreads();
  int o = t & 31, vg = t >> 5;
  for (int k = 0; k < 8; ++k) {
    int v = vg + 8 * k;
    float2 acc = make_float2(0.f, 0.f);
    for (int mm = 0; mm < 16; ++mm) {
      float2 w = twp[(mm * v) & 63];
      float2 vv = Vs[mm][o];
      acc.x += vv.x * w.x - vv.y * w.y;
      acc.y += vv.x * w.y + vv.y * w.x;
    }
    P[((long)(v * 64 + s) * NJZ + j) * CID + o] = acc;
  }
}

// ---------------- inverse real-z (16 bins -> 40) + accumulate, via MFMA GEMM.
// out[.., z, o] += sum_k A[z][k] * B[k][m];  A from g_invz table.
// Staging in uint LDS with odd row stride (21 dwords) -> conflict-free.
__global__ __launch_bounds__(256) void k_invzadd_mfma(const float2* __restrict__ Pb,
    float* __restrict__ out, long strideV, long strideS, int b0) {
  __shared__ __align__(16) char smem[21504]; // PsH+PsL=2*128*21*4=21504; Cs=40*132*4=21120
  unsigned (*PsH)[21] = (unsigned(*)[21])smem;
  unsigned (*PsL)[21] = (unsigned(*)[21])(smem + 10752);
  float (*Cs)[132] = (float(*)[132])smem;      // [z][m]
  int t = threadIdx.x;
  int wid = t >> 6, lane = t & 63;
  int l15 = lane & 15, quad = lane >> 4;
  int b = b0 + blockIdx.z;
  int vv = blockIdx.y;
  int s0 = blockIdx.x * 4;
  // A fragments from table (L2-resident)
  short8 AH[3], AL[3];
  for (int zt = 0; zt < 3; ++zt) {
    AH[zt] = *(const short8*)&g_invzAH[zt][lane][0];
    AL[zt] = *(const short8*)&g_invzAL[zt][lane][0];
  }
  // stage P[vv, s0..s0+3, j, o] -> Ps[m = sl*32+o][j]
  const float2* src = Pb + (long)blockIdx.z * R3SLOT + ((long)(vv * 64 + s0) * NJZ) * CID;
  for (int kk = t; kk < 16 * 128; kk += 256) {
    int j = kk >> 7, m = kk & 127;
    int sl = m >> 5, o = m & 31;
    float2 v = src[((long)sl * NJZ + j) * CID + o];
    unsigned short hx = f2bf(v.x), hy = f2bf(v.y);
    unsigned short lx = f2bf(v.x - bf2f(hx)), ly = f2bf(v.y - bf2f(hy));
    PsH[m][j] = (unsigned)hx | ((unsigned)hy << 16);
    PsL[m][j] = (unsigned)lx | ((unsigned)ly << 16);
  }
  __syncthreads();
  // read B fragments to registers before overwriting the union with C
  short8 bh[2], bl[2];
  for (int mt = 0; mt < 2; ++mt) {
    int mc = wid * 32 + mt * 16 + l15;
    union { unsigned u[4]; short8 s; } th, tl;
    for (int c = 0; c < 4; ++c) {
      th.u[c] = PsH[mc][quad * 4 + c];
      tl.u[c] = PsL[mc][quad * 4 + c];
    }
    bh[mt] = th.s; bl[mt] = tl.s;
  }
  __syncthreads();
  for (int mt = 0; mt < 2; ++mt) {
    int mc = wid * 32 + mt * 16;
    for (int zt = 0; zt < 3; ++zt) {
      float4v acc = {0.f, 0.f, 0.f, 0.f};
      acc = __builtin_amdgcn_mfma_f32_16x16x32_bf16(AL[zt], bh[mt], acc, 0, 0, 0);
      acc = __builtin_amdgcn_mfma_f32_16x16x32_bf16(AH[zt], bl[mt], acc, 0, 0, 0);
      acc = __builtin_amdgcn_mfma_f32_16x16x32_bf16(AH[zt], bh[mt], acc, 0, 0, 0);
      for (int r = 0; r < 4; ++r) {
        int z = zt * 16 + quad * 4 + r;
        if (z < 40) Cs[z][mc + l15] = acc[r];
      }
    }
  }
  __syncthreads();
  // vectorized RMW: out[s0+sl][z][o] += Cs[z][sl*32+o]
  float* obb = out + (long)b * (NXD * NYD * NZD * CID) + (long)vv * strideV
             + (long)s0 * strideS;
  for (int idx = t; idx < 4 * 40 * 8; idx += 256) {
    int sl = idx / 320, rem = idx - sl * 320;
    int z = rem >> 3, o4 = rem & 7;
    float4v* gp = (float4v*)(obb + (long)sl * strideS + z * 32 + o4 * 4);
    float4v g = *gp;
    float4v c = *(const float4v*)&Cs[z][sl * 32 + o4 * 4];
    g.x += c.x; g.y += c.y; g.z += c.z; g.w += c.w;
    *gp = g;
  }
}

// ---------------- xy branch: forward real-y DFT via MFMA (64 -> 32 bins)
// GEMM per (b,x): M=128 m-rows per block, K=64 (y), N=64 (n=jy*2+part)
// C accumulated in LDS [m][n], then coalesced float2 stores to S.
__global__ __launch_bounds__(256) void k_fwdy_mfma(const float* __restrict__ X,
    float2* __restrict__ Sb, int b0) {
  __shared__ __align__(16) char smem[35328]; // Xs=128*37*4=18944; Cs=128*69*4=35328
  unsigned (*Xs)[37] = (unsigned(*)[37])smem;   // [m][y2] packed bf16 pairs
  float (*Cs)[69] = (float(*)[69])smem;         // [m][n]
  int t = threadIdx.x;
  int wid = t >> 6, lane = t & 63;
  int l15 = lane & 15, quad = lane >> 4;
  int b = b0 + blockIdx.z;
  int x = blockIdx.y;
  int m0 = blockIdx.x * 128;
  // B fragments from table
  short8 Bf[2][4];
  for (int kt = 0; kt < 2; ++kt)
    for (int nt = 0; nt < 4; ++nt)
      Bf[kt][nt] = *(const short8*)&g_fwdyB[kt][nt][lane][0];
  // stage X[b,x,y,m0+..] -> Xs[m][y2] (two y per dword)
  const float* src = X + (((long)b * 64 + x) * 64) * 1280 + m0;
  for (int k = t; k < 32 * 128; k += 256) {
    int y2 = k >> 7, m = k & 127;
    float v0 = src[(long)(2 * y2) * 1280 + m];
    float v1 = src[(long)(2 * y2 + 1) * 1280 + m];
    Xs[m][y2] = (unsigned)f2bf(v0) | ((unsigned)f2bf(v1) << 16);
  }
  __syncthreads();
  // read A fragments (wave owns rows wid*32 .. wid*32+31)
  short8 a[2][2];  // [mt][kt]
  for (int mt = 0; mt < 2; ++mt) {
    int mrow = wid * 32 + mt * 16 + l15;
    for (int kt = 0; kt < 2; ++kt) {
      union { unsigned u[4]; short8 s; } tmp;
      for (int c = 0; c < 4; ++c) tmp.u[c] = Xs[mrow][kt * 16 + quad * 4 + c];
      a[mt][kt] = tmp.s;
    }
  }
  __syncthreads();
  for (int mt = 0; mt < 2; ++mt) {
    for (int nt = 0; nt < 4; ++nt) {
      float4v acc = {0.f, 0.f, 0.f, 0.f};
      acc = __builtin_amdgcn_mfma_f32_16x16x32_bf16(a[mt][0], Bf[0][nt], acc, 0, 0, 0);
      acc = __builtin_amdgcn_mfma_f32_16x16x32_bf16(a[mt][1], Bf[1][nt], acc, 0, 0, 0);
      int n = nt * 16 + l15;
      for (int r = 0; r < 4; ++r)
        Cs[wid * 32 + mt * 16 + quad * 4 + r][n] = acc[r];
    }
  }
  __syncthreads();
  // coalesced stores: S[jy*1280 + m0 + m] = (Cs[m][2jy], Cs[m][2jy+1])
  float2* S = Sb + (long)blockIdx.z * R1SLOT + (long)x * (NJY * NZD * CID) + m0;
  for (int idx = t; idx < 32 * 128; idx += 256) {
    int jy = idx >> 7, m = idx & 127;
    S[(long)jy * 1280 + m] = make_float2(Cs[m][2 * jy], Cs[m][2 * jy + 1]);
  }
}

// ---------------- xy branch: inverse x DFT (16 -> 64), unnormalized
__global__ __launch_bounds__(256) void k_invx_xy(const float2* __restrict__ V2b,
    float2* __restrict__ P2b) {
  __shared__ float2 Vs[16][CID];
  __shared__ float2 twp[64];
  int jy = blockIdx.x, z = blockIdx.y, t = threadIdx.x;
  const float2* V2 = V2b + (long)blockIdx.z * R2SLOT;
  float2* P2 = P2b + (long)blockIdx.z * R3SLOT;
  if (t < 64) {
    float s_, c_; sincosf(TWO_PI * t / 64.0f, &s_, &c_);
    twp[t] = make_float2(c_, s_);
  }
  for (int k = t; k < 512; k += 256) {
    int kx = k >> 5, o = k & 31;
    Vs[kx][o] = V2[(((long)kx * NJY + jy) * NZD + z) * CID + o];
  }
  __syncthreads();
  int o = t & 31, xg = t >> 5;
  for (int k = 0; k < 8; ++k) {
    int x = xg + 8 * k;
    float2 acc = make_float2(0.f, 0.f);
    for (int kx = 0; kx < 16; ++kx) {
      float2 w = twp[(kx * x) & 63];
      float2 v = Vs[kx][o];
      acc.x += v.x * w.x - v.y * w.y;
      acc.y += v.x * w.y + v.y * w.x;
    }
    P2[(((long)x * NJY + jy) * NZD + z) * CID + o] = acc;
  }
}

// ---------------- xy branch: inverse real-y (32 bins -> 64) + accumulate, via MFMA.
// out[..,y,m] += sum_k A[y][k] * B[k][m]; A from g_invy table.
// Staging in uint LDS [m][37] (odd stride -> conflict-free). C in LDS, float4 RMW.
__global__ __launch_bounds__(256) void k_invyadd_mfma(const float2* __restrict__ P2b,
    float* __restrict__ out, int b0) {
  __shared__ __align__(16) char smem[18944]; // PsH+PsL=2*64*37*4=18944; Cs=64*68*4=17408
  unsigned (*PsH)[37] = (unsigned(*)[37])smem;      // [m][jy]
  unsigned (*PsL)[37] = (unsigned(*)[37])(smem + 9472);
  float (*Cs)[68] = (float(*)[68])smem;             // [y][m]
  int t = threadIdx.x;
  int wid = t >> 6, lane = t & 63;
  int l15 = lane & 15, quad = lane >> 4;
  int b = b0 + blockIdx.z;
  int x = blockIdx.y;
  int m0 = blockIdx.x * 64;                    // 1280 m / 64 = 20 blocks
  // stage P2[x, jy, m0..m0+63] -> Ps[m][jy]
  const float2* src = P2b + (long)blockIdx.z * R3SLOT + (long)x * (NJY * NZD * CID) + m0;
  for (int kk = t; kk < 32 * 64; kk += 256) {
    int jy = kk >> 6, m = kk & 63;
    float2 v = src[(long)jy * (NZD * CID) + m];
    unsigned short hx = f2bf(v.x), hy = f2bf(v.y);
    unsigned short lx = f2bf(v.x - bf2f(hx)), ly = f2bf(v.y - bf2f(hy));
    PsH[m][jy] = (unsigned)hx | ((unsigned)hy << 16);
    PsL[m][jy] = (unsigned)lx | ((unsigned)ly << 16);
  }
  __syncthreads();
  // read B fragments to registers before overwriting the union with C
  int mc = wid * 16;
  short8 bh0, bh1, bl0, bl1;
  {
    union { unsigned u[4]; short8 s; } t0, t1, t2, t3;
    for (int c = 0; c < 4; ++c) {
      t0.u[c] = PsH[mc + l15][quad * 4 + c];
      t1.u[c] = PsH[mc + l15][16 + quad * 4 + c];
      t2.u[c] = PsL[mc + l15][quad * 4 + c];
      t3.u[c] = PsL[mc + l15][16 + quad * 4 + c];
    }
    bh0 = t0.s; bh1 = t1.s; bl0 = t2.s; bl1 = t3.s;
  }
  __syncthreads();
#pragma unroll 1
  for (int yt = 0; yt < 4; ++yt) {
    short8 AH0 = *(const short8*)&g_invyAH[0][yt][lane][0];
    short8 AH1 = *(const short8*)&g_invyAH[1][yt][lane][0];
    short8 AL0 = *(const short8*)&g_invyAL[0][yt][lane][0];
    short8 AL1 = *(const short8*)&g_invyAL[1][yt][lane][0];
    float4v acc = {0.f, 0.f, 0.f, 0.f};
    acc = __builtin_amdgcn_mfma_f32_16x16x32_bf16(AL0, bh0, acc, 0, 0, 0);
    acc = __builtin_amdgcn_mfma_f32_16x16x32_bf16(AL1, bh1, acc, 0, 0, 0);
    acc = __builtin_amdgcn_mfma_f32_16x16x32_bf16(AH0, bl0, acc, 0, 0, 0);
    acc = __builtin_amdgcn_mfma_f32_16x16x32_bf16(AH1, bl1, acc, 0, 0, 0);
    acc = __builtin_amdgcn_mfma_f32_16x16x32_bf16(AH0, bh0, acc, 0, 0, 0);
    acc = __builtin_amdgcn_mfma_f32_16x16x32_bf16(AH1, bh1, acc, 0, 0, 0);
    for (int r = 0; r < 4; ++r) {
      int y = yt * 16 + quad * 4 + r;
      Cs[y][mc + l15] = acc[r];
    }
  }
  __syncthreads();
  // vectorized RMW: out[..,y, m0+mf] += Cs[y][mf]
  float* ob = out + ((long)(b * 64 + x)) * (NYD * NZD * CID) + m0;
  for (int idx = t; idx < 64 * 16; idx += 256) {
    int y = idx >> 4, f = idx & 15;
    float4v* gp = (float4v*)(ob + (long)y * (NZD * CID) + f * 4);
    float4v g = *gp;
    float4v c = *(const float4v*)&Cs[y][f * 4];
    g.x += c.x; g.y += c.y; g.z += c.z; g.w += c.w;
    *gp = g;
  }
}

// ---------------- FFN via MFMA, in-place on out.
__global__ __launch_bounds__(256) void k_ff_mfma(float* __restrict__ out,
    const float* __restrict__ W0, const float* __restrict__ b0,
    const float* __restrict__ W1, const float* __restrict__ b1) {
  __shared__ unsigned short h1s[4][16 * 64];
  int t = threadIdx.x;
  int wid = t >> 6, lane = t & 63;
  int l15 = lane & 15, quad = lane >> 4;
  short8 B1[4];
  float bb0[4];
  for (int nt = 0; nt < 4; ++nt) {
    int hh = nt * 16 + l15;
    for (int j = 0; j < 8; ++j) B1[nt][j] = (short)f2bf(W0[hh * 32 + quad * 8 + j]);
    bb0[nt] = b0[hh];
  }
  short8 B2[2][2];
  float bb1[2];
  for (int k0 = 0; k0 < 2; ++k0)
    for (int nt = 0; nt < 2; ++nt) {
      int o = nt * 16 + l15;
      for (int j = 0; j < 8; ++j)
        B2[k0][nt][j] = (short)f2bf(W1[o * 64 + k0 * 32 + quad * 8 + j]);
    }
  for (int nt = 0; nt < 2; ++nt) bb1[nt] = b1[nt * 16 + l15];

  const int TOT = 40960;
  int wg = blockIdx.x * 4 + wid;
  unsigned short* hs = h1s[wid];
  for (int tt = wg; tt < TOT; tt += gridDim.x * 4) {
    long r0 = (long)tt * 16;
    const float4v* p = (const float4v*)(out + (r0 + l15) * 32 + quad * 8);
    float4v x0 = p[0], x1 = p[1];
    short8 a1;
    for (int j = 0; j < 4; ++j) { a1[j] = (short)f2bf(x0[j]); a1[4 + j] = (short)f2bf(x1[j]); }
    for (int nt = 0; nt < 4; ++nt) {
      float4v acc = {0.f, 0.f, 0.f, 0.f};
      acc = __builtin_amdgcn_mfma_f32_16x16x32_bf16(a1, B1[nt], acc, 0, 0, 0);
      for (int r = 0; r < 4; ++r) {
        float v = acc[r] + bb0[nt];
        v = v > 0.f ? v : 0.f;
        hs[(quad * 4 + r) * 64 + nt * 16 + l15] = f2bf(v);
      }
    }
    short8 a2[2];
    for (int k0 = 0; k0 < 2; ++k0)
      a2[k0] = *(const short8*)&hs[l15 * 64 + k0 * 32 + quad * 8];
    for (int nt = 0; nt < 2; ++nt) {
      float4v acc = {0.f, 0.f, 0.f, 0.f};
      acc = __builtin_amdgcn_mfma_f32_16x16x32_bf16(a2[0], B2[0][nt], acc, 0, 0, 0);
      acc = __builtin_amdgcn_mfma_f32_16x16x32_bf16(a2[1], B2[1][nt], acc, 0, 0, 0);
      for (int r = 0; r < 4; ++r)
        out[(r0 + quad * 4 + r) * 32 + nt * 16 + l15] = acc[r] + bb1[nt];
    }
  }
}

extern "C" void kernel_launch(void* const* d_in, const int* in_sizes, int n_in,
                              void* d_out, int out_size, void* d_ws, size_t ws_size,
                              hipStream_t stream) {
  const float* X       = (const float*)d_in[0];
  const float* w_w     = (const float*)d_in[1];
  const float* w_b     = (const float*)d_in[2];
  const float* fw_xy   = (const float*)d_in[3];
  const float* fw_yz   = (const float*)d_in[4];
  const float* fw_xz   = (const float*)d_in[5];
  const float* fw2_xy  = (const float*)d_in[6];
  const float* fw2_yz  = (const float*)d_in[7];
  const float* fw2_xz  = (const float*)d_in[8];
  const float* ff_w0   = (const float*)d_in[9];
  const float* ff_b0   = (const float*)d_in[10];
  const float* ff_w1   = (const float*)d_in[11];
  const float* ff_b1   = (const float*)d_in[12];
  float* out = (float*)d_out;
  char* ws = (char*)d_ws;

  const size_t need_full = (size_t)(R1SLOT + R2SLOT + R3SLOT) * 4 * 8;
  bool full = ws_size >= need_full;

  float2 *r1, *r2, *r3;
  if (full) {
    r1 = (float2*)ws;
    r2 = (float2*)(ws + (size_t)R1SLOT * 4 * 8);
    r3 = (float2*)(ws + (size_t)(R1SLOT + R2SLOT) * 4 * 8);
  } else {
    r1 = (float2*)ws;
    r2 = (float2*)(ws + (size_t)R1SLOT * 8);
    r3 = (float2*)(ws + (size_t)(R1SLOT + R2SLOT) * 8);
  }

  k_twprep<<<dim3(4), dim3(256), 0, stream>>>();
  k_conv_mfma<<<dim3(2560), dim3(256), 0, stream>>>(X, w_w, w_b, out);

  int nz = full ? 4 : 1;
  int nb = full ? 1 : 4;
  for (int b = 0; b < nb; ++b) {
    // shared z-projection for xz & yz (T in r1)
    k_zproj<<<dim3(1024, 1, nz), dim3(512), 0, stream>>>(X, r1, b);
    // ---- xz branch: contract x. T idx: x*32768 + y*512 + j*32 + i
    k_fwddft<<<dim3(32, 8, nz), dim3(256), 0, stream>>>(r1, r3, 32768, 512, 32);
    k_mix<<<dim3(16, 16, nz), dim3(256), 0, stream>>>(r3, r2, fw_xz, fw2_xz,
        8, 8, 32768, 32, 512, 64);
    k_invaxis<<<dim3(64, 16, nz), dim3(256), 0, stream>>>(r2, r3);
    k_invzadd_mfma<<<dim3(16, 64, nz), dim3(256), 0, stream>>>(r3, out, 64 * 40 * 32, 40 * 32, b);
    // ---- yz branch: contract y. T idx: y*512 + x*32768 + j*32 + i
    k_fwddft<<<dim3(32, 8, nz), dim3(256), 0, stream>>>(r1, r3, 512, 32768, 32);
    k_mix<<<dim3(16, 16, nz), dim3(256), 0, stream>>>(r3, r2, fw_yz, fw2_yz,
        8, 8, 32768, 32, 512, 64);
    k_invaxis<<<dim3(64, 16, nz), dim3(256), 0, stream>>>(r2, r3);
    k_invzadd_mfma<<<dim3(16, 64, nz), dim3(256), 0, stream>>>(r3, out, 40 * 32, 64 * 40 * 32, b);
    // ---- xy branch (S in r1): S idx: x*40960 + jy*1280 + z*32 + i
    k_fwdy_mfma<<<dim3(10, 64, nz), dim3(256), 0, stream>>>(X, r1, b);
    k_fwddft<<<dim3(64, 5, nz), dim3(256), 0, stream>>>(r1, r3, 40960, 32, 1280);
    k_mix<<<dim3(16, 32, nz), dim3(256), 0, stream>>>(r3, r2, fw_xy, fw2_xy,
        16, 16, 40960, 1280, 32, 40);
    k_invx_xy<<<dim3(32, 40, nz), dim3(256), 0, stream>>>(r2, r3);
    k_invyadd_mfma<<<dim3(20, 64, nz), dim3(256), 0, stream>>>(r3, out, b);
  }

  k_ff_mfma<<<dim3(2560), dim3(256), 0, stream>>>(out, ff_w0, ff_b0, ff_w1, ff_b1);
}